// Round 1
// 681.592 us; speedup vs baseline: 1.0459x; 1.0459x over previous
//
#include <hip/hip_runtime.h>
#include <hip/hip_bf16.h>

typedef __bf16 bf16x8 __attribute__((ext_vector_type(8)));
typedef __bf16 bf16x4 __attribute__((ext_vector_type(4)));
typedef float f32x4 __attribute__((ext_vector_type(4)));

// Direct global->LDS async copy, 16B per lane. LDS dest must be the
// wave-uniform base; HW places lane i at base + i*16B. Global src is per-lane.
__device__ __forceinline__ void async_copy16(__bf16* lds_base, const __bf16* g) {
  __builtin_amdgcn_global_load_lds(
      (const __attribute__((address_space(1))) void*)g,
      (__attribute__((address_space(3))) void*)lds_base, 16, 0, 0);
}

// ---------------- f32 -> bf16 conversion (4 elems/thread) ----------------
__global__ __launch_bounds__(256) void cvt_bf16(const float* __restrict__ in,
                                                __bf16* __restrict__ out, int n4) {
  int i = blockIdx.x * 256 + threadIdx.x;
  if (i >= n4) return;
  float4 v = ((const float4*)in)[i];
  bf16x4 o;
  o.x = (__bf16)v.x; o.y = (__bf16)v.y; o.z = (__bf16)v.z; o.w = (__bf16)v.w;
  ((bf16x4*)out)[i] = o;
}

// ---------------- small GEMM (kept for kv): 128x128 tile, m97 pattern ----
template<bool STORE_BF16>
__global__ __launch_bounds__(256) void gemm_bt(const __bf16* __restrict__ A,
                                               const __bf16* __restrict__ Bw,
                                               const float* __restrict__ bias,
                                               void* __restrict__ Cp,
                                               int M, int N, int K) {
  __shared__ __align__(16) __bf16 sA[128 * 64];
  __shared__ __align__(16) __bf16 sB[128 * 64];
  const int tid = threadIdx.x;
  const int lane = tid & 63;
  const int w = tid >> 6;
  const int wr = w >> 1, wc = w & 1;
  const int l15 = lane & 15, q4 = lane >> 4;
  const int bm = blockIdx.x, bn = blockIdx.y;

  f32x4 acc[4][4] = {};

  for (int k0 = 0; k0 < K; k0 += 64) {
    __syncthreads();
#pragma unroll
    for (int it = 0; it < 4; ++it) {
      int chunk = it * 256 + tid;
      int row = chunk >> 3, c8 = chunk & 7;
      int ldsbase = (it * 256 + w * 64) * 8;
      async_copy16(sA + ldsbase, A + (size_t)(bm * 128 + row) * K + k0 + c8 * 8);
      async_copy16(sB + ldsbase, Bw + (size_t)(bn * 128 + row) * K + k0 + c8 * 8);
    }
    __syncthreads();
#pragma unroll
    for (int kk = 0; kk < 2; ++kk) {
      bf16x8 af[4], bfr[4];
#pragma unroll
      for (int i = 0; i < 4; ++i)
        af[i] = *(const bf16x8*)(sA + (wr * 64 + i * 16 + l15) * 64 + kk * 32 + q4 * 8);
#pragma unroll
      for (int j = 0; j < 4; ++j)
        bfr[j] = *(const bf16x8*)(sB + (wc * 64 + j * 16 + l15) * 64 + kk * 32 + q4 * 8);
#pragma unroll
      for (int i = 0; i < 4; ++i)
#pragma unroll
        for (int j = 0; j < 4; ++j)
          acc[i][j] = __builtin_amdgcn_mfma_f32_16x16x32_bf16(af[i], bfr[j], acc[i][j], 0, 0, 0);
    }
  }
#pragma unroll
  for (int j = 0; j < 4; ++j) {
    const int col = bn * 128 + wc * 64 + j * 16 + l15;
    const float bv = bias[col];
#pragma unroll
    for (int i = 0; i < 4; ++i) {
      const int row0 = bm * 128 + wr * 64 + i * 16 + q4 * 4;
#pragma unroll
      for (int r = 0; r < 4; ++r) {
        float v = acc[i][j][r] + bv;
        size_t off = (size_t)(row0 + r) * N + col;
        if (STORE_BF16) ((__bf16*)Cp)[off] = (__bf16)v;
        else            ((float*)Cp)[off]  = v;
      }
    }
  }
}

// ---------------- big GEMM: 256x256 tile, BK=32, ring-4 counted-vmcnt ----
// 512 threads = 8 waves (2M x 4N); per-wave output 128x64. LDS: 4 slots x
// (A 256x32 + B 256x32) bf16 = 128 KiB. Prefetch distance 3 tiles; in-loop
// wait is vmcnt(8) (tiles t+2,t+3 stay in flight), epilogue drains 8->4->0.
// Swizzle: 16B chunk c of row r stored at c^(r&3); applied on the global
// source (gload_lds dest linear) and on the ds_read address.
template<int KK, bool STORE_BF16>
__global__ __launch_bounds__(512, 2) void gemm_bt_big(const __bf16* __restrict__ A,
                                                      const __bf16* __restrict__ Bw,
                                                      const float* __restrict__ bias,
                                                      void* __restrict__ Cp,
                                                      int N) {
  static_assert(KK % 32 == 0 && KK / 32 >= 4, "KK");
  constexpr int NT = KK / 32;          // K-tiles of 32
  __shared__ __align__(16) __bf16 sA[4 * 256 * 32];
  __shared__ __align__(16) __bf16 sB[4 * 256 * 32];
  const int tid = threadIdx.x;
  const int lane = tid & 63;
  const int w = tid >> 6;
  const int wr = w >> 2, wc = w & 3;
  const int l15 = lane & 15, q4 = lane >> 4;
  const int bm = blockIdx.x, bn = blockIdx.y;

  // staging map: chunk ch = it*512 + tid; row = ch>>2; stored chunk = ch&3,
  // sourced from logical chunk (ch&3)^(row&3)  (128 % 4 == 0 -> same for it=1)
  const int r0 = tid >> 2;
  const int csw = (tid & 3) ^ (r0 & 3);
  const __bf16* gA0 = A + (size_t)(bm * 256 + r0) * KK + csw * 8;
  const __bf16* gA1 = gA0 + (size_t)128 * KK;
  const __bf16* gB0 = Bw + (size_t)(bn * 256 + r0) * KK + csw * 8;
  const __bf16* gB1 = gB0 + (size_t)128 * KK;
  const int lds_w0 = (w * 64) * 8;            // wave-uniform dest, it=0
  const int lds_w1 = (512 + w * 64) * 8;      // it=1

  // ds_read bases (elements); logical chunk q4 of row R lives at phys q4^(R&3),
  // R&3 == l15&3 for all fragment rows (bases are multiples of 16).
  const int qsw = (q4 ^ (l15 & 3)) * 8;
  const int aBase = (wr * 128 + l15) * 32 + qsw;
  const int bBase = (wc * 64 + l15) * 32 + qsw;

  f32x4 acc[8][4] = {};

  // prologue: stage tiles 0,1,2 (12 issues/thread), wait tile 0 (leave 8)
#pragma unroll
  for (int t = 0; t < 3; ++t) {
    async_copy16(sA + t * 8192 + lds_w0, gA0 + t * 32);
    async_copy16(sA + t * 8192 + lds_w1, gA1 + t * 32);
    async_copy16(sB + t * 8192 + lds_w0, gB0 + t * 32);
    async_copy16(sB + t * 8192 + lds_w1, gB1 + t * 32);
  }
  asm volatile("s_waitcnt vmcnt(8)" ::: "memory");
  __builtin_amdgcn_s_barrier();
  __builtin_amdgcn_sched_barrier(0);

#pragma unroll 4
  for (int t = 0; t < NT; ++t) {
    const __bf16* sAs = sA + (t & 3) * 8192;
    const __bf16* sBs = sB + (t & 3) * 8192;
    const int ps = (t + 3) & 3;
    const bool pf = (t + 3) < NT;

    // ---- phase A: ds-read a(mh0)+b, stage A of tile t+3, MFMA m=0..3 ----
    bf16x8 af[4], bfrag[4];
#pragma unroll
    for (int m = 0; m < 4; ++m)
      af[m] = *(const bf16x8*)(sAs + aBase + m * 512);
#pragma unroll
    for (int n = 0; n < 4; ++n)
      bfrag[n] = *(const bf16x8*)(sBs + bBase + n * 512);
    if (pf) {
      async_copy16(sA + ps * 8192 + lds_w0, gA0 + (t + 3) * 32);
      async_copy16(sA + ps * 8192 + lds_w1, gA1 + (t + 3) * 32);
    }
    __builtin_amdgcn_s_barrier();
    asm volatile("s_waitcnt lgkmcnt(0)" ::: "memory");
    __builtin_amdgcn_sched_barrier(0);
    __builtin_amdgcn_s_setprio(1);
#pragma unroll
    for (int m = 0; m < 4; ++m)
#pragma unroll
      for (int n = 0; n < 4; ++n)
        acc[m][n] = __builtin_amdgcn_mfma_f32_16x16x32_bf16(af[m], bfrag[n], acc[m][n], 0, 0, 0);
    __builtin_amdgcn_s_setprio(0);
    __builtin_amdgcn_s_barrier();
    __builtin_amdgcn_sched_barrier(0);

    // ---- phase B: ds-read a(mh1), stage B of t+3, counted vmcnt, m=4..7 ----
    bf16x8 ag[4];
#pragma unroll
    for (int m = 0; m < 4; ++m)
      ag[m] = *(const bf16x8*)(sAs + aBase + 2048 + m * 512);
    if (pf) {
      async_copy16(sB + ps * 8192 + lds_w0, gB0 + (t + 3) * 32);
      async_copy16(sB + ps * 8192 + lds_w1, gB1 + (t + 3) * 32);
    }
    // ensure tile t+1 resident before next iteration's reads; never drain
    // to 0 while later tiles are in flight (T4).
    if (pf)                 asm volatile("s_waitcnt vmcnt(8)" ::: "memory");
    else if (t + 3 == NT)   asm volatile("s_waitcnt vmcnt(4)" ::: "memory");
    else if (t + 2 == NT)   asm volatile("s_waitcnt vmcnt(0)" ::: "memory");
    __builtin_amdgcn_s_barrier();
    asm volatile("s_waitcnt lgkmcnt(0)" ::: "memory");
    __builtin_amdgcn_sched_barrier(0);
    __builtin_amdgcn_s_setprio(1);
#pragma unroll
    for (int m = 0; m < 4; ++m)
#pragma unroll
      for (int n = 0; n < 4; ++n)
        acc[4 + m][n] = __builtin_amdgcn_mfma_f32_16x16x32_bf16(ag[m], bfrag[n], acc[4 + m][n], 0, 0, 0);
    __builtin_amdgcn_s_setprio(0);
    __builtin_amdgcn_s_barrier();
    __builtin_amdgcn_sched_barrier(0);
  }

#pragma unroll
  for (int n = 0; n < 4; ++n) {
    const int col = bn * 256 + wc * 64 + n * 16 + l15;
    const float bv = bias[col];
#pragma unroll
    for (int m = 0; m < 8; ++m) {
      const int row0 = bm * 256 + wr * 128 + m * 16 + q4 * 4;
#pragma unroll
      for (int r = 0; r < 4; ++r) {
        float v = acc[m][n][r] + bv;
        size_t off = (size_t)(row0 + r) * N + col;
        if (STORE_BF16) ((__bf16*)Cp)[off] = (__bf16)v;
        else            ((float*)Cp)[off]  = v;
      }
    }
  }
}

// ---------------- kv epilogue: LN(k) -> K (b,nh,s2,d); v -> V^T (b,nh,d,s2)
__global__ __launch_bounds__(256) void kv_epilogue(const float* __restrict__ kv,
                                                   const float* __restrict__ g,
                                                   const float* __restrict__ bta,
                                                   __bf16* __restrict__ Kd,
                                                   __bf16* __restrict__ VT) {
  const int lane = threadIdx.x & 63;
  const int vec = blockIdx.x * 4 + (threadIdx.x >> 6);
  const int nh = vec & 15;
  const int sv = (vec >> 4) & 1;
  const int row = vec >> 5;
  const int b = row >> 8, s2 = row & 255;
  float v = kv[(size_t)row * 2048 + sv * 1024 + nh * 64 + lane];
  if (sv == 0) {
    float mu = v;
#pragma unroll
    for (int o = 32; o; o >>= 1) mu += __shfl_xor(mu, o);
    mu *= (1.f / 64.f);
    float d = v - mu;
    float va = d * d;
#pragma unroll
    for (int o = 32; o; o >>= 1) va += __shfl_xor(va, o);
    va *= (1.f / 64.f);
    float xn = d * rsqrtf(va + 1e-6f) * g[lane] + bta[lane];
    Kd[(((size_t)b * 16 + nh) * 256 + s2) * 64 + lane] = (__bf16)xn;
  } else {
    VT[(((size_t)b * 16 + nh) * 64 + lane) * 256 + s2] = (__bf16)v;
  }
}

// ---------------- q epilogue: LN + 2D-RoPE + *SCALE -> Q (b,nh,s1,d) ------
__global__ __launch_bounds__(256) void q_epilogue(const __bf16* __restrict__ qraw,
                                                  const float* __restrict__ g,
                                                  const float* __restrict__ bta,
                                                  __bf16* __restrict__ Q) {
  const int lane = threadIdx.x & 63;
  const int vec = blockIdx.x * 4 + (threadIdx.x >> 6);
  const int nh = vec & 15;
  const int row = vec >> 4;
  float v = (float)qraw[(size_t)row * 1024 + nh * 64 + lane];
  float mu = v;
#pragma unroll
  for (int o = 32; o; o >>= 1) mu += __shfl_xor(mu, o);
  mu *= (1.f / 64.f);
  float d = v - mu;
  float va = d * d;
#pragma unroll
  for (int o = 32; o; o >>= 1) va += __shfl_xor(va, o);
  va *= (1.f / 64.f);
  float xn = d * rsqrtf(va + 1e-6f) * g[lane] + bta[lane];
  const int s1 = row & 4095;
  const int hh = s1 >> 6, wpix = s1 & 63;
  const int t = lane >> 2;
  const int usew = (lane >> 1) & 1;
  float inv = __expf(-(float)t * 0.5756462732485114f);
  float ang = (usew ? (float)wpix : (float)hh) * inv;
  float cc = __cosf(ang), ssn = __sinf(ang);
  float partner = __shfl_xor(xn, 1);
  float rot = xn * cc + partner * ssn * ((lane & 1) ? 1.f : -1.f);
  rot *= 0.125f;
  const int b = row >> 12;
  Q[(((size_t)b * 16 + nh) * 4096 + (size_t)s1) * 64 + lane] = (__bf16)rot;
}

// ---------------- fused attention: per (b,nh, 64-row q tile) --------------
__global__ __launch_bounds__(256) void attn_kernel(const __bf16* __restrict__ Q,
                                                   const __bf16* __restrict__ Kd,
                                                   const __bf16* __restrict__ VT,
                                                   __bf16* __restrict__ O) {
  __shared__ __align__(16) __bf16 sK[256 * 64];
  __shared__ __align__(16) __bf16 sV[64 * 256];
  const int tid = threadIdx.x, lane = tid & 63, w = tid >> 6;
  const int l15 = lane & 15, q4 = lane >> 4;
  const int s7 = l15 & 7;
  const int bh = blockIdx.y;
  const int m0 = blockIdx.x * 64;
  const __bf16* Kg = Kd + (size_t)bh * 256 * 64;
  const __bf16* Vg = VT + (size_t)bh * 64 * 256;
  const __bf16* Qg = Q + ((size_t)bh * 4096 + m0) * 64;
#pragma unroll
  for (int it = 0; it < 8; ++it) {
    int c = it * 256 + tid;
    int kr = c >> 3, kh = c & 7;
    *(uint4*)(sK + kr * 64 + ((kh ^ (kr & 7)) * 8)) = *(const uint4*)(Kg + c * 8);
    int vr = c >> 5, vh = c & 31;
    *(uint4*)(sV + vr * 256 + ((vh ^ (vr & 7)) * 8)) = *(const uint4*)(Vg + c * 8);
  }
  bf16x8 qf0 = *(const bf16x8*)(Qg + (w * 16 + l15) * 64 + q4 * 8);
  bf16x8 qf1 = *(const bf16x8*)(Qg + (w * 16 + l15) * 64 + 32 + q4 * 8);
  __syncthreads();
  f32x4 sacc[16] = {};
#pragma unroll
  for (int mt = 0; mt < 16; ++mt) {
    bf16x8 a0 = *(const bf16x8*)(sK + (mt * 16 + l15) * 64 + ((q4 ^ s7) * 8));
    bf16x8 a1 = *(const bf16x8*)(sK + (mt * 16 + l15) * 64 + (((4 + q4) ^ s7) * 8));
    sacc[mt] = __builtin_amdgcn_mfma_f32_16x16x32_bf16(a0, qf0, sacc[mt], 0, 0, 0);
    sacc[mt] = __builtin_amdgcn_mfma_f32_16x16x32_bf16(a1, qf1, sacc[mt], 0, 0, 0);
  }
  __syncthreads();
  float mx = -1e30f;
#pragma unroll
  for (int mt = 0; mt < 16; ++mt)
#pragma unroll
    for (int r = 0; r < 4; ++r) mx = fmaxf(mx, sacc[mt][r]);
  mx = fmaxf(mx, __shfl_xor(mx, 16));
  mx = fmaxf(mx, __shfl_xor(mx, 32));
  float l = 0.f;
#pragma unroll
  for (int mt = 0; mt < 16; ++mt)
#pragma unroll
    for (int r = 0; r < 4; ++r) {
      float p = __expf(sacc[mt][r] - mx);
      sacc[mt][r] = p;
      l += p;
    }
  l += __shfl_xor(l, 16);
  l += __shfl_xor(l, 32);
  const float linv = 1.f / l;
#pragma unroll
  for (int mt = 0; mt < 16; ++mt) {
    bf16x4 pk;
    pk.x = (__bf16)(sacc[mt][0] * linv);
    pk.y = (__bf16)(sacc[mt][1] * linv);
    pk.z = (__bf16)(sacc[mt][2] * linv);
    pk.w = (__bf16)(sacc[mt][3] * linv);
    int chunk = mt * 2 + (q4 >> 1);
    *(bf16x4*)(sK + (w * 16 + l15) * 256 + ((chunk ^ s7) * 8) + (q4 & 1) * 4) = pk;
  }
  f32x4 oacc[4] = {};
#pragma unroll
  for (int ks = 0; ks < 8; ++ks) {
    int phys = ((ks * 4 + q4) ^ s7) * 8;
    bf16x8 a = *(const bf16x8*)(sK + (w * 16 + l15) * 256 + phys);
#pragma unroll
    for (int j = 0; j < 4; ++j) {
      bf16x8 b = *(const bf16x8*)(sV + (j * 16 + l15) * 256 + phys);
      oacc[j] = __builtin_amdgcn_mfma_f32_16x16x32_bf16(a, b, oacc[j], 0, 0, 0);
    }
  }
  const int b = bh >> 4, nh = bh & 15;
#pragma unroll
  for (int j = 0; j < 4; ++j)
#pragma unroll
    for (int r = 0; r < 4; ++r) {
      size_t off = ((size_t)b * 4096 + m0 + w * 16 + q4 * 4 + r) * 1024
                 + nh * 64 + j * 16 + l15;
      O[off] = (__bf16)oacc[j][r];
    }
}

extern "C" void kernel_launch(void* const* d_in, const int* in_sizes, int n_in,
                              void* d_out, int out_size, void* d_ws, size_t ws_size,
                              hipStream_t stream) {
  const float* x    = (const float*)d_in[0];
  const float* y    = (const float*)d_in[1];
  const float* wq   = (const float*)d_in[2];
  const float* bq   = (const float*)d_in[3];
  const float* wkv  = (const float*)d_in[4];
  const float* bkv  = (const float*)d_in[5];
  const float* wo   = (const float*)d_in[6];
  const float* bo   = (const float*)d_in[7];
  const float* qng  = (const float*)d_in[8];
  const float* qnb  = (const float*)d_in[9];
  const float* kng  = (const float*)d_in[10];
  const float* knb  = (const float*)d_in[11];
  float* out = (float*)d_out;

  char* ws = (char*)d_ws;
  size_t off = 0;
  auto take = [&](size_t bytes) { char* p = ws + off; off += (bytes + 255) & ~(size_t)255; return p; };
  __bf16* xb   = (__bf16*)take((size_t)32768 * 1024 * 2);
  char*  reg1  = take((size_t)32768 * 1024 * 2);
  __bf16* Qb   = (__bf16*)take((size_t)32768 * 1024 * 2);
  __bf16* yb   = (__bf16*)take((size_t)2048 * 2048 * 2);
  __bf16* wqb  = (__bf16*)take((size_t)1024 * 1024 * 2);
  __bf16* wkvb = (__bf16*)take((size_t)2048 * 2048 * 2);
  __bf16* wob  = (__bf16*)take((size_t)1024 * 1024 * 2);
  __bf16* Kb   = (__bf16*)take((size_t)128 * 256 * 64 * 2);
  __bf16* VTb  = (__bf16*)take((size_t)128 * 64 * 256 * 2);
  float*  kvf  = (float*)reg1;
  __bf16* qraw = (__bf16*)reg1;
  __bf16* aout = xb;

  cvt_bf16<<<32768, 256, 0, stream>>>(x,   xb,   8388608);
  cvt_bf16<<<4096,  256, 0, stream>>>(y,   yb,   1048576);
  cvt_bf16<<<1024,  256, 0, stream>>>(wq,  wqb,  262144);
  cvt_bf16<<<4096,  256, 0, stream>>>(wkv, wkvb, 1048576);
  cvt_bf16<<<1024,  256, 0, stream>>>(wo,  wob,  262144);

  // kv = y @ wkv^T + bkv  (f32 out), then LN(k)->K, v->V^T
  gemm_bt<false><<<dim3(16, 16), 256, 0, stream>>>(yb, wkvb, bkv, kvf, 2048, 2048, 2048);
  kv_epilogue<<<16384, 256, 0, stream>>>(kvf, kng, knb, Kb, VTb);

  // q_raw = x @ wq^T + bq (bf16 out), then LN + RoPE + scale -> Q
  gemm_bt_big<1024, true><<<dim3(128, 4), 512, 0, stream>>>(xb, wqb, bq, qraw, 1024);
  q_epilogue<<<131072, 256, 0, stream>>>(qraw, qng, qnb, Qb);

  // fused attention -> aout (b,s1,nh*hd) bf16
  attn_kernel<<<dim3(64, 128), 256, 0, stream>>>(Qb, Kb, VTb, aout);

  // out = aout @ wo^T + bo (f32 out)
  gemm_bt_big<1024, false><<<dim3(128, 4), 512, 0, stream>>>(aout, wob, bo, out, 1024);
}

// Round 2
// 600.038 us; speedup vs baseline: 1.1880x; 1.1359x over previous
//
#include <hip/hip_runtime.h>
#include <hip/hip_bf16.h>

typedef __bf16 bf16x8 __attribute__((ext_vector_type(8)));
typedef __bf16 bf16x4 __attribute__((ext_vector_type(4)));
typedef float f32x4 __attribute__((ext_vector_type(4)));

// Direct global->LDS async copy, 16B per lane. LDS dest must be the
// wave-uniform base; HW places lane i at base + i*16B. Global src is per-lane.
__device__ __forceinline__ void async_copy16(__bf16* lds_base, const __bf16* g) {
  __builtin_amdgcn_global_load_lds(
      (const __attribute__((address_space(1))) void*)g,
      (__attribute__((address_space(3))) void*)lds_base, 16, 0, 0);
}

// ---------------- f32 -> bf16 conversion (4 elems/thread) ----------------
__global__ __launch_bounds__(256) void cvt_bf16(const float* __restrict__ in,
                                                __bf16* __restrict__ out, int n4) {
  int i = blockIdx.x * 256 + threadIdx.x;
  if (i >= n4) return;
  float4 v = ((const float4*)in)[i];
  bf16x4 o;
  o.x = (__bf16)v.x; o.y = (__bf16)v.y; o.z = (__bf16)v.z; o.w = (__bf16)v.w;
  ((bf16x4*)out)[i] = o;
}

// ---------------- small GEMM (kept for kv): 128x128 tile, m97 pattern ----
template<bool STORE_BF16>
__global__ __launch_bounds__(256) void gemm_bt(const __bf16* __restrict__ A,
                                               const __bf16* __restrict__ Bw,
                                               const float* __restrict__ bias,
                                               void* __restrict__ Cp,
                                               int M, int N, int K) {
  __shared__ __align__(16) __bf16 sA[128 * 64];
  __shared__ __align__(16) __bf16 sB[128 * 64];
  const int tid = threadIdx.x;
  const int lane = tid & 63;
  const int w = tid >> 6;
  const int wr = w >> 1, wc = w & 1;
  const int l15 = lane & 15, q4 = lane >> 4;
  const int bm = blockIdx.x, bn = blockIdx.y;

  f32x4 acc[4][4] = {};

  for (int k0 = 0; k0 < K; k0 += 64) {
    __syncthreads();
#pragma unroll
    for (int it = 0; it < 4; ++it) {
      int chunk = it * 256 + tid;
      int row = chunk >> 3, c8 = chunk & 7;
      int ldsbase = (it * 256 + w * 64) * 8;
      async_copy16(sA + ldsbase, A + (size_t)(bm * 128 + row) * K + k0 + c8 * 8);
      async_copy16(sB + ldsbase, Bw + (size_t)(bn * 128 + row) * K + k0 + c8 * 8);
    }
    __syncthreads();
#pragma unroll
    for (int kk = 0; kk < 2; ++kk) {
      bf16x8 af[4], bfr[4];
#pragma unroll
      for (int i = 0; i < 4; ++i)
        af[i] = *(const bf16x8*)(sA + (wr * 64 + i * 16 + l15) * 64 + kk * 32 + q4 * 8);
#pragma unroll
      for (int j = 0; j < 4; ++j)
        bfr[j] = *(const bf16x8*)(sB + (wc * 64 + j * 16 + l15) * 64 + kk * 32 + q4 * 8);
#pragma unroll
      for (int i = 0; i < 4; ++i)
#pragma unroll
        for (int j = 0; j < 4; ++j)
          acc[i][j] = __builtin_amdgcn_mfma_f32_16x16x32_bf16(af[i], bfr[j], acc[i][j], 0, 0, 0);
    }
  }
#pragma unroll
  for (int j = 0; j < 4; ++j) {
    const int col = bn * 128 + wc * 64 + j * 16 + l15;
    const float bv = bias[col];
#pragma unroll
    for (int i = 0; i < 4; ++i) {
      const int row0 = bm * 128 + wr * 64 + i * 16 + q4 * 4;
#pragma unroll
      for (int r = 0; r < 4; ++r) {
        float v = acc[i][j][r] + bv;
        size_t off = (size_t)(row0 + r) * N + col;
        if (STORE_BF16) ((__bf16*)Cp)[off] = (__bf16)v;
        else            ((float*)Cp)[off]  = v;
      }
    }
  }
}

// ---------------- big GEMM: 256x256 tile, BK=64, m201-style 4 phases -----
// 512 threads = 8 waves (2M x 4N); per-wave output 128x64. LDS: 2 buffers x
// (A 256x64 + B 256x64) bf16 = 128 KiB. Rows are 128B = 8 chunks of 16B;
// XOR-8 swizzle: logical chunk c of row r stored at phys c^(r&7) (applied on
// the pre-swizzled global source; gload_lds dest stays linear).
// Per tile, 4 quadrant phases of 16 MFMA: (m0,n0),(m0,n1),(m1,n0),(m1,n1).
// B frags are register-cached across m-halves -> ds_reads/phase = 12,4,8,0.
// Half-tile staging ordered by slot retirement:
//   ph0: Bh1(t+1)->dead buf   ph1: Ah1(t+1)->dead buf
//   ph2: Ah0(t+2)->live buf (slot retired ph0)   ph3: Bh0(t+2)->live buf
// One s_waitcnt vmcnt(4) per tile (end of ph3); drains to 0 only at tail.
// A halves: rows {0-63,128-191} / {64-127,192-255}; B halves by bit5 of row.
template<int KK, int EPI>
__global__ __launch_bounds__(512, 2) void gemm_big(const __bf16* __restrict__ A,
                                                   const __bf16* __restrict__ Bw,
                                                   const float* __restrict__ bias,
                                                   void* __restrict__ Cp,
                                                   const float* __restrict__ g,
                                                   const float* __restrict__ bt,
                                                   int N) {
  constexpr int NT = KK / 64;
  static_assert(NT >= 3, "need >=3 K-tiles");
  __shared__ __align__(16) __bf16 sA[2][256 * 64];
  __shared__ __align__(16) __bf16 sB[2][256 * 64];
  const int tid = threadIdx.x;
  const int lane = tid & 63;
  const int w = tid >> 6;
  const int wr = w >> 2, wc = w & 3;
  const int l15 = lane & 15, q4 = lane >> 4;
  const int bm = blockIdx.x, bn = blockIdx.y;

  // staging geometry: per issue, a wave covers 8 consecutive rows x 8 chunks.
  const int rl = lane >> 3;            // row within the wave's 8-row stripe
  const int cs = (lane & 7) ^ rl;      // pre-swizzled source chunk (phys=lane&7)
  const __bf16* Ag = A + (size_t)(bm * 256) * KK + cs * 8;
  const __bf16* Bg = Bw + (size_t)(bn * 256) * KK + cs * 8;
  const int gbA = w * 8;                        // A half h: +h*64; issue1: +128
  const int gbB = (w & 3) * 8 + (w >> 2) * 64;  // B half h: +h*32; issue1: +128

  auto STAGE_A = [&](int bb, int t, int h) {
    int gb = gbA + h * 64;
    async_copy16(&sA[bb][gb * 64],         Ag + (size_t)(gb + rl) * KK + t * 64);
    async_copy16(&sA[bb][(gb + 128) * 64], Ag + (size_t)(gb + 128 + rl) * KK + t * 64);
  };
  auto STAGE_B = [&](int bb, int t, int h) {
    int gb = gbB + h * 32;
    async_copy16(&sB[bb][gb * 64],         Bg + (size_t)(gb + rl) * KK + t * 64);
    async_copy16(&sB[bb][(gb + 128) * 64], Bg + (size_t)(gb + 128 + rl) * KK + t * 64);
  };

  // ds_read fragment addressing: row&7 == l15&7 for all frag rows, so
  // phys chunk = (kk*4+q4) ^ (l15&7).
  const int pc0 = ((q4) ^ (l15 & 7)) * 8;
  const int pc1 = ((4 + q4) ^ (l15 & 7)) * 8;
  const int arow0 = (wr * 128 + l15) * 64;
  const int brow0 = (wc * 64 + l15) * 64;

  f32x4 acc[8][4] = {};

  // prologue: tile0 fully, plus Ah0,Bh0 of tile1; wait tile0 (leave 4 in flight)
  STAGE_A(0, 0, 0); STAGE_B(0, 0, 0); STAGE_B(0, 0, 1); STAGE_A(0, 0, 1);
  STAGE_A(1, 1, 0); STAGE_B(1, 1, 0);
  asm volatile("s_waitcnt vmcnt(4)" ::: "memory");
  __builtin_amdgcn_s_barrier();
  __builtin_amdgcn_sched_barrier(0);

#pragma unroll 2
  for (int t = 0; t < NT; ++t) {
    const int cb = t & 1, nb = cb ^ 1;
    const __bf16* sAc = sA[cb];
    const __bf16* sBc = sB[cb];
    bf16x8 a[4][2], b0[2][2], b1[2][2];

    // ---- ph0: read a(m0-3)+b(n0-1), stage Bh1(t+1), MFMA (m0,n0) ----
#pragma unroll
    for (int m = 0; m < 4; ++m) {
      a[m][0] = *(const bf16x8*)(sAc + arow0 + m * 1024 + pc0);
      a[m][1] = *(const bf16x8*)(sAc + arow0 + m * 1024 + pc1);
    }
#pragma unroll
    for (int n = 0; n < 2; ++n) {
      b0[n][0] = *(const bf16x8*)(sBc + brow0 + n * 1024 + pc0);
      b0[n][1] = *(const bf16x8*)(sBc + brow0 + n * 1024 + pc1);
    }
    if (t + 1 < NT) STAGE_B(nb, t + 1, 1);
    __builtin_amdgcn_s_barrier();
    asm volatile("s_waitcnt lgkmcnt(0)" ::: "memory");
    __builtin_amdgcn_sched_barrier(0);
    __builtin_amdgcn_s_setprio(1);
#pragma unroll
    for (int m = 0; m < 4; ++m)
#pragma unroll
      for (int n = 0; n < 2; ++n) {
        acc[m][n] = __builtin_amdgcn_mfma_f32_16x16x32_bf16(a[m][0], b0[n][0], acc[m][n], 0, 0, 0);
        acc[m][n] = __builtin_amdgcn_mfma_f32_16x16x32_bf16(a[m][1], b0[n][1], acc[m][n], 0, 0, 0);
      }
    __builtin_amdgcn_s_setprio(0);
    __builtin_amdgcn_s_barrier();
    __builtin_amdgcn_sched_barrier(0);

    // ---- ph1: read b(n2-3), stage Ah1(t+1), MFMA (m0,n1) ----
#pragma unroll
    for (int n = 0; n < 2; ++n) {
      b1[n][0] = *(const bf16x8*)(sBc + brow0 + (2 + n) * 1024 + pc0);
      b1[n][1] = *(const bf16x8*)(sBc + brow0 + (2 + n) * 1024 + pc1);
    }
    if (t + 1 < NT) STAGE_A(nb, t + 1, 1);
    __builtin_amdgcn_s_barrier();
    asm volatile("s_waitcnt lgkmcnt(0)" ::: "memory");
    __builtin_amdgcn_sched_barrier(0);
    __builtin_amdgcn_s_setprio(1);
#pragma unroll
    for (int m = 0; m < 4; ++m)
#pragma unroll
      for (int n = 0; n < 2; ++n) {
        acc[m][2 + n] = __builtin_amdgcn_mfma_f32_16x16x32_bf16(a[m][0], b1[n][0], acc[m][2 + n], 0, 0, 0);
        acc[m][2 + n] = __builtin_amdgcn_mfma_f32_16x16x32_bf16(a[m][1], b1[n][1], acc[m][2 + n], 0, 0, 0);
      }
    __builtin_amdgcn_s_setprio(0);
    __builtin_amdgcn_s_barrier();
    __builtin_amdgcn_sched_barrier(0);

    // ---- ph2: read a(m4-7), stage Ah0(t+2), MFMA (m1,n0) ----
#pragma unroll
    for (int m = 0; m < 4; ++m) {
      a[m][0] = *(const bf16x8*)(sAc + arow0 + (4 + m) * 1024 + pc0);
      a[m][1] = *(const bf16x8*)(sAc + arow0 + (4 + m) * 1024 + pc1);
    }
    if (t + 2 < NT) STAGE_A(cb, t + 2, 0);
    __builtin_amdgcn_s_barrier();
    asm volatile("s_waitcnt lgkmcnt(0)" ::: "memory");
    __builtin_amdgcn_sched_barrier(0);
    __builtin_amdgcn_s_setprio(1);
#pragma unroll
    for (int m = 0; m < 4; ++m)
#pragma unroll
      for (int n = 0; n < 2; ++n) {
        acc[4 + m][n] = __builtin_amdgcn_mfma_f32_16x16x32_bf16(a[m][0], b0[n][0], acc[4 + m][n], 0, 0, 0);
        acc[4 + m][n] = __builtin_amdgcn_mfma_f32_16x16x32_bf16(a[m][1], b0[n][1], acc[4 + m][n], 0, 0, 0);
      }
    __builtin_amdgcn_s_setprio(0);
    __builtin_amdgcn_s_barrier();
    __builtin_amdgcn_sched_barrier(0);

    // ---- ph3: stage Bh0(t+2), counted wait, MFMA (m1,n1) ----
    if (t + 2 < NT) STAGE_B(cb, t + 2, 0);
    if (t + 2 < NT)      { asm volatile("s_waitcnt vmcnt(4)" ::: "memory"); }
    else if (t + 1 < NT) { asm volatile("s_waitcnt vmcnt(0)" ::: "memory"); }
    __builtin_amdgcn_s_barrier();
    __builtin_amdgcn_sched_barrier(0);
    __builtin_amdgcn_s_setprio(1);
#pragma unroll
    for (int m = 0; m < 4; ++m)
#pragma unroll
      for (int n = 0; n < 2; ++n) {
        acc[4 + m][2 + n] = __builtin_amdgcn_mfma_f32_16x16x32_bf16(a[m][0], b1[n][0], acc[4 + m][2 + n], 0, 0, 0);
        acc[4 + m][2 + n] = __builtin_amdgcn_mfma_f32_16x16x32_bf16(a[m][1], b1[n][1], acc[4 + m][2 + n], 0, 0, 0);
      }
    __builtin_amdgcn_s_setprio(0);
    __builtin_amdgcn_s_barrier();
    __builtin_amdgcn_sched_barrier(0);
  }

  if (EPI == 0) {
    // plain f32 store + bias
#pragma unroll
    for (int n = 0; n < 4; ++n) {
      const int col = bn * 256 + wc * 64 + n * 16 + l15;
      const float bv = bias[col];
#pragma unroll
      for (int m = 0; m < 8; ++m) {
        const int row0 = bm * 256 + wr * 128 + m * 16 + q4 * 4;
#pragma unroll
        for (int r = 0; r < 4; ++r)
          ((float*)Cp)[(size_t)(row0 + r) * N + col] = acc[m][n][r] + bv;
      }
    }
  } else {
    // fused q epilogue: +bias, LN over the head (64 cols, all owned by this
    // wave: 4 in-register + 16-lane shfl reduce), 2D RoPE, *SCALE, write
    // Q (b,nh,s1,d) bf16 directly.
    const int nh = bn * 4 + wc;
    const int usew = (l15 >> 1) & 1;
    const float sgn = (l15 & 1) ? 1.f : -1.f;
    float gq[4], bqv[4], inv[4], bv[4];
#pragma unroll
    for (int n = 0; n < 4; ++n) {
      const int d = n * 16 + l15;
      gq[n] = g[d]; bqv[n] = bt[d];
      bv[n] = bias[nh * 64 + d];
      inv[n] = __expf(-(float)(d >> 2) * 0.5756462732485114f);
    }
#pragma unroll
    for (int m = 0; m < 8; ++m) {
#pragma unroll
      for (int r = 0; r < 4; ++r) {
        const int row = bm * 256 + wr * 128 + m * 16 + q4 * 4 + r;
        const int s1 = row & 4095, bidx = row >> 12;
        const float base = usew ? (float)(s1 & 63) : (float)(s1 >> 6);
        float v[4];
        float sum = 0.f;
#pragma unroll
        for (int n = 0; n < 4; ++n) { v[n] = acc[m][n][r] + bv[n]; sum += v[n]; }
        sum += __shfl_xor(sum, 1); sum += __shfl_xor(sum, 2);
        sum += __shfl_xor(sum, 4); sum += __shfl_xor(sum, 8);
        const float mu = sum * (1.f / 64.f);
        float sq = 0.f;
#pragma unroll
        for (int n = 0; n < 4; ++n) { v[n] -= mu; sq += v[n] * v[n]; }
        sq += __shfl_xor(sq, 1); sq += __shfl_xor(sq, 2);
        sq += __shfl_xor(sq, 4); sq += __shfl_xor(sq, 8);
        const float rs = rsqrtf(sq * (1.f / 64.f) + 1e-6f);
        __bf16* Qrow = (__bf16*)Cp + ((size_t)(bidx * 16 + nh) * 4096 + s1) * 64;
#pragma unroll
        for (int n = 0; n < 4; ++n) {
          const float xn = v[n] * rs * gq[n] + bqv[n];
          const float ang = base * inv[n];
          const float cc = __cosf(ang), ssn = __sinf(ang);
          const float partner = __shfl_xor(xn, 1);
          const float rot = (xn * cc + partner * ssn * sgn) * 0.125f;
          Qrow[n * 16 + l15] = (__bf16)rot;
        }
      }
    }
  }
}

// ---------------- kv epilogue: LN(k) -> K (b,nh,s2,d); v -> V^T (b,nh,d,s2)
__global__ __launch_bounds__(256) void kv_epilogue(const float* __restrict__ kv,
                                                   const float* __restrict__ g,
                                                   const float* __restrict__ bta,
                                                   __bf16* __restrict__ Kd,
                                                   __bf16* __restrict__ VT) {
  const int lane = threadIdx.x & 63;
  const int vec = blockIdx.x * 4 + (threadIdx.x >> 6);
  const int nh = vec & 15;
  const int sv = (vec >> 4) & 1;
  const int row = vec >> 5;
  const int b = row >> 8, s2 = row & 255;
  float v = kv[(size_t)row * 2048 + sv * 1024 + nh * 64 + lane];
  if (sv == 0) {
    float mu = v;
#pragma unroll
    for (int o = 32; o; o >>= 1) mu += __shfl_xor(mu, o);
    mu *= (1.f / 64.f);
    float d = v - mu;
    float va = d * d;
#pragma unroll
    for (int o = 32; o; o >>= 1) va += __shfl_xor(va, o);
    va *= (1.f / 64.f);
    float xn = d * rsqrtf(va + 1e-6f) * g[lane] + bta[lane];
    Kd[(((size_t)b * 16 + nh) * 256 + s2) * 64 + lane] = (__bf16)xn;
  } else {
    VT[(((size_t)b * 16 + nh) * 64 + lane) * 256 + s2] = (__bf16)v;
  }
}

// ---------------- fused attention: per (b,nh, 64-row q tile) --------------
__global__ __launch_bounds__(256) void attn_kernel(const __bf16* __restrict__ Q,
                                                   const __bf16* __restrict__ Kd,
                                                   const __bf16* __restrict__ VT,
                                                   __bf16* __restrict__ O) {
  __shared__ __align__(16) __bf16 sK[256 * 64];
  __shared__ __align__(16) __bf16 sV[64 * 256];
  const int tid = threadIdx.x, lane = tid & 63, w = tid >> 6;
  const int l15 = lane & 15, q4 = lane >> 4;
  const int s7 = l15 & 7;
  const int bh = blockIdx.y;
  const int m0 = blockIdx.x * 64;
  const __bf16* Kg = Kd + (size_t)bh * 256 * 64;
  const __bf16* Vg = VT + (size_t)bh * 64 * 256;
  const __bf16* Qg = Q + ((size_t)bh * 4096 + m0) * 64;
#pragma unroll
  for (int it = 0; it < 8; ++it) {
    int c = it * 256 + tid;
    int kr = c >> 3, kh = c & 7;
    *(uint4*)(sK + kr * 64 + ((kh ^ (kr & 7)) * 8)) = *(const uint4*)(Kg + c * 8);
    int vr = c >> 5, vh = c & 31;
    *(uint4*)(sV + vr * 256 + ((vh ^ (vr & 7)) * 8)) = *(const uint4*)(Vg + c * 8);
  }
  bf16x8 qf0 = *(const bf16x8*)(Qg + (w * 16 + l15) * 64 + q4 * 8);
  bf16x8 qf1 = *(const bf16x8*)(Qg + (w * 16 + l15) * 64 + 32 + q4 * 8);
  __syncthreads();
  f32x4 sacc[16] = {};
#pragma unroll
  for (int mt = 0; mt < 16; ++mt) {
    bf16x8 a0 = *(const bf16x8*)(sK + (mt * 16 + l15) * 64 + ((q4 ^ s7) * 8));
    bf16x8 a1 = *(const bf16x8*)(sK + (mt * 16 + l15) * 64 + (((4 + q4) ^ s7) * 8));
    sacc[mt] = __builtin_amdgcn_mfma_f32_16x16x32_bf16(a0, qf0, sacc[mt], 0, 0, 0);
    sacc[mt] = __builtin_amdgcn_mfma_f32_16x16x32_bf16(a1, qf1, sacc[mt], 0, 0, 0);
  }
  __syncthreads();
  float mx = -1e30f;
#pragma unroll
  for (int mt = 0; mt < 16; ++mt)
#pragma unroll
    for (int r = 0; r < 4; ++r) mx = fmaxf(mx, sacc[mt][r]);
  mx = fmaxf(mx, __shfl_xor(mx, 16));
  mx = fmaxf(mx, __shfl_xor(mx, 32));
  float l = 0.f;
#pragma unroll
  for (int mt = 0; mt < 16; ++mt)
#pragma unroll
    for (int r = 0; r < 4; ++r) {
      float p = __expf(sacc[mt][r] - mx);
      sacc[mt][r] = p;
      l += p;
    }
  l += __shfl_xor(l, 16);
  l += __shfl_xor(l, 32);
  const float linv = 1.f / l;
#pragma unroll
  for (int mt = 0; mt < 16; ++mt) {
    bf16x4 pk;
    pk.x = (__bf16)(sacc[mt][0] * linv);
    pk.y = (__bf16)(sacc[mt][1] * linv);
    pk.z = (__bf16)(sacc[mt][2] * linv);
    pk.w = (__bf16)(sacc[mt][3] * linv);
    int chunk = mt * 2 + (q4 >> 1);
    *(bf16x4*)(sK + (w * 16 + l15) * 256 + ((chunk ^ s7) * 8) + (q4 & 1) * 4) = pk;
  }
  f32x4 oacc[4] = {};
#pragma unroll
  for (int ks = 0; ks < 8; ++ks) {
    int phys = ((ks * 4 + q4) ^ s7) * 8;
    bf16x8 a = *(const bf16x8*)(sK + (w * 16 + l15) * 256 + phys);
#pragma unroll
    for (int j = 0; j < 4; ++j) {
      bf16x8 b = *(const bf16x8*)(sV + (j * 16 + l15) * 256 + phys);
      oacc[j] = __builtin_amdgcn_mfma_f32_16x16x32_bf16(a, b, oacc[j], 0, 0, 0);
    }
  }
  const int b = bh >> 4, nh = bh & 15;
#pragma unroll
  for (int j = 0; j < 4; ++j)
#pragma unroll
    for (int r = 0; r < 4; ++r) {
      size_t off = ((size_t)b * 4096 + m0 + w * 16 + q4 * 4 + r) * 1024
                 + nh * 64 + j * 16 + l15;
      O[off] = (__bf16)oacc[j][r];
    }
}

extern "C" void kernel_launch(void* const* d_in, const int* in_sizes, int n_in,
                              void* d_out, int out_size, void* d_ws, size_t ws_size,
                              hipStream_t stream) {
  const float* x    = (const float*)d_in[0];
  const float* y    = (const float*)d_in[1];
  const float* wq   = (const float*)d_in[2];
  const float* bq   = (const float*)d_in[3];
  const float* wkv  = (const float*)d_in[4];
  const float* bkv  = (const float*)d_in[5];
  const float* wo   = (const float*)d_in[6];
  const float* bo   = (const float*)d_in[7];
  const float* qng  = (const float*)d_in[8];
  const float* qnb  = (const float*)d_in[9];
  const float* kng  = (const float*)d_in[10];
  const float* knb  = (const float*)d_in[11];
  float* out = (float*)d_out;

  char* ws = (char*)d_ws;
  size_t off = 0;
  auto take = [&](size_t bytes) { char* p = ws + off; off += (bytes + 255) & ~(size_t)255; return p; };
  __bf16* xb   = (__bf16*)take((size_t)32768 * 1024 * 2);
  char*  reg1  = take((size_t)32768 * 1024 * 2);
  __bf16* Qb   = (__bf16*)take((size_t)32768 * 1024 * 2);
  __bf16* yb   = (__bf16*)take((size_t)2048 * 2048 * 2);
  __bf16* wqb  = (__bf16*)take((size_t)1024 * 1024 * 2);
  __bf16* wkvb = (__bf16*)take((size_t)2048 * 2048 * 2);
  __bf16* wob  = (__bf16*)take((size_t)1024 * 1024 * 2);
  __bf16* Kb   = (__bf16*)take((size_t)128 * 256 * 64 * 2);
  __bf16* VTb  = (__bf16*)take((size_t)128 * 64 * 256 * 2);
  float*  kvf  = (float*)reg1;
  __bf16* aout = xb;

  cvt_bf16<<<32768, 256, 0, stream>>>(x,   xb,   8388608);
  cvt_bf16<<<4096,  256, 0, stream>>>(y,   yb,   1048576);
  cvt_bf16<<<1024,  256, 0, stream>>>(wq,  wqb,  262144);
  cvt_bf16<<<4096,  256, 0, stream>>>(wkv, wkvb, 1048576);
  cvt_bf16<<<1024,  256, 0, stream>>>(wo,  wob,  262144);

  // kv = y @ wkv^T + bkv  (f32 out), then LN(k)->K, v->V^T
  gemm_bt<false><<<dim3(16, 16), 256, 0, stream>>>(yb, wkvb, bkv, kvf, 2048, 2048, 2048);
  kv_epilogue<<<16384, 256, 0, stream>>>(kvf, kng, knb, Kb, VTb);

  // Q = RoPE(LN(x @ wq^T + bq)) * SCALE, fused in the GEMM epilogue
  gemm_big<1024, 2><<<dim3(128, 4), 512, 0, stream>>>(xb, wqb, bq, Qb, qng, qnb, 1024);

  // fused attention -> aout (b,s1,nh*hd) bf16
  attn_kernel<<<dim3(64, 128), 256, 0, stream>>>(Qb, Kb, VTb, aout);

  // out = aout @ wo^T + bo (f32 out)
  gemm_big<1024, 0><<<dim3(128, 4), 512, 0, stream>>>(aout, wob, bo, out, nullptr, nullptr, 1024);
}